// Round 1
// baseline (183.407 us; speedup 1.0000x reference)
//
#include <hip/hip_runtime.h>
#include <math.h>

#define NB   262144   // batch (tokens)
#define DD   512      // d_routing
#define NG   4        // groups
#define NGS  4        // group size
#define NOUT 20       // 4 group logits + 16 in-group logits

__global__ __launch_bounds__(256, 4) void router_k(
    const float* __restrict__ x,        // [NB, DD]
    const float* __restrict__ group_w,  // [NG, DD]
    const float* __restrict__ group_b,  // [NG]
    const float* __restrict__ in_w,     // [NG, NGS, DD]
    const float* __restrict__ in_b,     // [NG, NGS]
    const int*   __restrict__ experts,  // [NG, NGS]
    float*       __restrict__ out)      // [2*NB*2]: indices then weights, fp32
{
    __shared__ float wlds[NOUT * DD];   // 40 KB: rows 0..3 = group_w, 4..19 = in_w
    {
        const float4* gw4 = reinterpret_cast<const float4*>(group_w);
        const float4* iw4 = reinterpret_cast<const float4*>(in_w);
        float4* wl4 = reinterpret_cast<float4*>(wlds);
        for (int i = threadIdx.x; i < (NG * DD) / 4; i += 256)
            wl4[i] = gw4[i];
        for (int i = threadIdx.x; i < (NG * NGS * DD) / 4; i += 256)
            wl4[(NG * DD) / 4 + i] = iw4[i];
    }
    __syncthreads();

    const int t = blockIdx.x * 256 + threadIdx.x;  // one token per thread
    const float* xr = x + (size_t)t * DD;

    float acc[NOUT];
#pragma unroll
    for (int o = 0; o < NOUT; ++o) acc[o] = 0.f;

    // Stream the token row; LDS weight reads are wave-uniform (broadcast).
    for (int dd = 0; dd < DD; dd += 16) {
        float4 xv[4];
#pragma unroll
        for (int j = 0; j < 4; ++j)
            xv[j] = *reinterpret_cast<const float4*>(xr + dd + 4 * j);
#pragma unroll
        for (int j = 0; j < 4; ++j) {
#pragma unroll
            for (int o = 0; o < NOUT; ++o) {
                const float4 w =
                    *reinterpret_cast<const float4*>(&wlds[o * DD + dd + 4 * j]);
                acc[o] = fmaf(xv[j].x, w.x, acc[o]);
                acc[o] = fmaf(xv[j].y, w.y, acc[o]);
                acc[o] = fmaf(xv[j].z, w.z, acc[o]);
                acc[o] = fmaf(xv[j].w, w.w, acc[o]);
            }
        }
    }

    // ---- group argmax (first-max tie-break, matches jnp.argmax) ----
    float gl[NG];
#pragma unroll
    for (int g = 0; g < NG; ++g) gl[g] = acc[g] + group_b[g];
    int bg = 0;
    float bv = gl[0];
#pragma unroll
    for (int g = 1; g < NG; ++g)
        if (gl[g] > bv) { bv = gl[g]; bg = g; }

    // ---- select chosen group's in-logits without runtime indexing (rule #20) ----
    float il[NGS];
#pragma unroll
    for (int k = 0; k < NGS; ++k) il[k] = 0.f;
#pragma unroll
    for (int g = 0; g < NG; ++g) {
        const bool sel = (g == bg);
#pragma unroll
        for (int k = 0; k < NGS; ++k)
            il[k] = sel ? acc[NG + g * NGS + k] : il[k];
    }
#pragma unroll
    for (int k = 0; k < NGS; ++k) il[k] += in_b[bg * NGS + k];

    // ---- softmax (fp32, subtract-max, matches jax.nn.softmax) ----
    float m = fmaxf(fmaxf(il[0], il[1]), fmaxf(il[2], il[3]));
    float p[NGS];
    float s = 0.f;
#pragma unroll
    for (int k = 0; k < NGS; ++k) { p[k] = expf(il[k] - m); s += p[k]; }
    const float inv = 1.0f / s;
#pragma unroll
    for (int k = 0; k < NGS; ++k) p[k] *= inv;

    // ---- top-2 on probs (descending, lower-index-on-tie, matches lax.top_k) ----
    int i1 = 0;
    float v1 = p[0];
#pragma unroll
    for (int k = 1; k < NGS; ++k)
        if (p[k] > v1) { v1 = p[k]; i1 = k; }
    int i2 = -1;
    float v2 = -3.0e38f;
#pragma unroll
    for (int k = 0; k < NGS; ++k)
        if (k != i1 && p[k] > v2) { v2 = p[k]; i2 = k; }

    // ---- map to global expert ids via experts_table ----
    const int id1 = experts[bg * NGS + i1];
    const int id2 = experts[bg * NGS + i2];

    // ---- write: [expert_indices (as f32) | top_weights], coalesced float2 ----
    float2* outi = reinterpret_cast<float2*>(out);
    float2* outw = reinterpret_cast<float2*>(out + (size_t)NB * 2);
    outi[t] = make_float2((float)id1, (float)id2);
    outw[t] = make_float2(v1, v2);
}

extern "C" void kernel_launch(void* const* d_in, const int* in_sizes, int n_in,
                              void* d_out, int out_size, void* d_ws, size_t ws_size,
                              hipStream_t stream) {
    const float* x  = (const float*)d_in[0];
    const float* gw = (const float*)d_in[1];
    const float* gb = (const float*)d_in[2];
    const float* iw = (const float*)d_in[3];
    const float* ib = (const float*)d_in[4];
    const int*   et = (const int*)d_in[5];
    float* out = (float*)d_out;

    router_k<<<dim3(NB / 256), dim3(256), 0, stream>>>(x, gw, gb, iw, ib, et, out);
}